// Round 5
// baseline (245.040 us; speedup 1.0000x reference)
//
#include <hip/hip_runtime.h>
#include <hip/hip_fp16.h>
#include <math.h>

#define NN 50000
#define NE 800000
#define RAWSTRIDE 96           // raw row stride (u16 col slots) per node
#define NBUCK 196              // node buckets of 256 (50000 -> 196)
#define NBBIN 196              // bin blocks: ceil(NE/ACH)
#define BCAP 4608              // per-bucket edge capacity (mean 4082, +8 sigma)
#define ACH 4096               // edges per bin block
#define G1B 782                // ceil(NN/64) gemm1 row-blocks
#define G2B 1563               // ceil(NN/32) agg row-blocks

using bf8v = __attribute__((ext_vector_type(8))) short;   // 8 bf16 (4 VGPRs)
using f4v  = __attribute__((ext_vector_type(4))) float;   // 4 fp32 acc

__device__ inline unsigned short f2bf(float f) {          // RNE f32->bf16
    unsigned int u = __float_as_uint(f);
    u += 0x7FFFu + ((u >> 16) & 1u);
    return (unsigned short)(u >> 16);
}
__device__ inline float bflo(unsigned int d) { return __uint_as_float(d << 16); }
__device__ inline float bfhi(unsigned int d) { return __uint_as_float(d & 0xFFFF0000u); }

// ---------------- prep: pack W1,W2 -> bf16 [n][k] in global; zero gcursor ----------------
// Replaces the hipMemsetAsync launch. 64 blocks x 256 = 16384 threads = 2*128*64 packed words.

__global__ __launch_bounds__(256) void prep_kernel(const float* __restrict__ W1,
                                                   const float* __restrict__ W2,
                                                   unsigned int* __restrict__ w1p,
                                                   unsigned int* __restrict__ w2p,
                                                   int* __restrict__ gcursor) {
    int id = blockIdx.x * 256 + threadIdx.x;
    int m = id >> 13;
    int rest = id & 8191;
    int n = rest >> 6;
    int kp = rest & 63;
    int k = kp * 2;
    const float* W = m ? W2 : W1;
    unsigned int* o = m ? w2p : w1p;
    unsigned int p = (unsigned int)f2bf(W[k * 128 + n]) |
                     ((unsigned int)f2bf(W[(k + 1) * 128 + n]) << 16);
    o[n * 64 + kp] = p;
    if (id < NBUCK) gcursor[id] = 0;
}

// ---------------- CSR build phase A: bin edges by dst>>8 ----------------

__device__ __forceinline__ void bin_body(const int* __restrict__ src,
                                         const int* __restrict__ dst,
                                         int* __restrict__ gcursor,
                                         unsigned int* __restrict__ bst,
                                         int bx, char* shc) {
    unsigned int* items = (unsigned int*)shc;            // ACH*4 = 16384 B
    int* cnt    = (int*)(shc + 16384);                   // 1024 B
    int* pref   = (int*)(shc + 17408);                   // 1028 B
    int* gstart = (int*)(shc + 18436);                   // 1024 B
    const int t = threadIdx.x;
    cnt[t] = 0;
    __syncthreads();
    const int base = bx * ACH;

    unsigned int my[16]; int myb[16], myr[16];
    #pragma unroll
    for (int i = 0; i < 16; ++i) {
        int e = base + i * 256 + t;
        my[i] = 0; myb[i] = -1; myr[i] = 0;
        if (e < NE) {
            int d = dst[e], s = src[e];
            my[i] = (unsigned int)s | ((unsigned int)d << 16);
            int b = d >> 8;
            myb[i] = b;
            myr[i] = atomicAdd(&cnt[b], 1);
        }
    }
    __syncthreads();
    if (t == 0) {
        int run = 0;
        for (int b = 0; b < 256; ++b) { pref[b] = run; run += cnt[b]; }
        pref[256] = run;
    }
    __syncthreads();
    if (cnt[t] > 0) gstart[t] = atomicAdd(&gcursor[t], cnt[t]);
    __syncthreads();
    #pragma unroll
    for (int i = 0; i < 16; ++i)
        if (myb[i] >= 0) items[pref[myb[i]] + myr[i]] = my[i];
    __syncthreads();
    const int total = pref[256];
    for (int i = t; i < total; i += 256) {
        int lo = 0, hi = 255;                // last b with pref[b] <= i
        while (lo < hi) { int mid = (lo + hi + 1) >> 1; if (pref[mid] <= i) lo = mid; else hi = mid - 1; }
        int idx = gstart[lo] + (i - pref[lo]);
        if (idx < BCAP) bst[(size_t)lo * BCAP + idx] = items[i];
    }
}

// ---------------- CSR build phase B: per-bucket LDS counting sort + dinv ----------------

__global__ __launch_bounds__(512) void sortb_kernel(const int* __restrict__ gcursor,
                                                    const unsigned int* __restrict__ bst,
                                                    int* __restrict__ cnt_g,
                                                    float* __restrict__ dinv,
                                                    unsigned short* __restrict__ raw) {
    __shared__ unsigned int items[BCAP];
    __shared__ int cnt[256], pref[257], cur[256];
    __shared__ unsigned short outl[BCAP];
    const int b = blockIdx.x;
    const int t = threadIdx.x;
    int n = gcursor[b];
    if (n > BCAP) n = BCAP;
    if (t < 256) { cnt[t] = 0; cur[t] = 0; }
    __syncthreads();
    for (int i = t; i < n; i += 512) {
        unsigned int u = bst[(size_t)b * BCAP + i];
        items[i] = u;
        atomicAdd(&cnt[(u >> 16) & 255], 1);
    }
    __syncthreads();
    if (t == 0) {
        int run = 0;
        for (int j = 0; j < 256; ++j) { pref[j] = run; run += cnt[j]; }
        pref[256] = run;
    }
    __syncthreads();
    for (int i = t; i < n; i += 512) {
        unsigned int u = items[i];
        int ln = (u >> 16) & 255;
        int r = atomicAdd(&cur[ln], 1);
        outl[pref[ln] + r] = (unsigned short)(u & 0xFFFFu);
    }
    __syncthreads();
    for (int i = t; i < n; i += 512) {
        int lo = 0, hi = 255;
        while (lo < hi) { int mid = (lo + hi + 1) >> 1; if (pref[mid] <= i) lo = mid; else hi = mid - 1; }
        int r = i - pref[lo];
        if (r < RAWSTRIDE) raw[(size_t)(b * 256 + lo) * RAWSTRIDE + r] = outl[i];
    }
    if (t < 256) {
        int node = b * 256 + t;
        if (node < NN) {
            int c = cnt[t];
            cnt_g[node] = c;
            dinv[node] = rsqrtf((float)(1 + c));
        }
    }
}

// ---------------- layer-1 MFMA GEMM body: B-frags direct from packed global W ----------------

__device__ __forceinline__ void gemm128_body_f32(const float* __restrict__ A,
                                                 const unsigned short* __restrict__ Wbf,
                                                 unsigned short* __restrict__ out,
                                                 int bx, char* shc) {
    unsigned short* Dt = (unsigned short*)shc;            // [64][136] bf16 out staging
    const int t = threadIdx.x;
    const int row0 = bx * 64;
    const int wave = t >> 6;
    const int l64  = t & 63;
    const int m16  = l64 & 15;
    const int quad = l64 >> 4;
    const int arow = row0 + wave * 16 + m16;
    const int arowc = (arow < NN) ? arow : 0;

    f4v acc[8];
    #pragma unroll
    for (int i = 0; i < 8; ++i) acc[i] = (f4v)(0.0f);

    #pragma unroll
    for (int k0 = 0; k0 < 128; k0 += 32) {
        bf8v afrag;
        const float4* ap = (const float4*)(A + (size_t)arowc * 128 + k0 + quad * 8);
        float4 a0 = ap[0], a1 = ap[1];
        afrag[0] = (short)f2bf(a0.x); afrag[1] = (short)f2bf(a0.y);
        afrag[2] = (short)f2bf(a0.z); afrag[3] = (short)f2bf(a0.w);
        afrag[4] = (short)f2bf(a1.x); afrag[5] = (short)f2bf(a1.y);
        afrag[6] = (short)f2bf(a1.z); afrag[7] = (short)f2bf(a1.w);
        #pragma unroll
        for (int nt = 0; nt < 8; ++nt) {
            bf8v bfrag = *(const bf8v*)(Wbf + (nt * 16 + m16) * 128 + k0 + quad * 8);
            acc[nt] = __builtin_amdgcn_mfma_f32_16x16x32_bf16(afrag, bfrag, acc[nt], 0, 0, 0);
        }
    }

    #pragma unroll
    for (int nt = 0; nt < 8; ++nt) {
        #pragma unroll
        for (int r = 0; r < 4; ++r) {
            Dt[(wave * 16 + quad * 4 + r) * 136 + nt * 16 + m16] = f2bf(acc[nt][r]);
        }
    }
    __syncthreads();

    #pragma unroll
    for (int j = 0; j < 4; ++j) {
        int idx = j * 256 + t;
        int r = idx >> 4, c4 = idx & 15;
        int gr = row0 + r;
        if (gr < NN)
            ((uint4*)(out + (size_t)gr * 128))[c4] = ((const uint4*)&Dt[r * 136])[c4];
    }
}

// fused: bin (196 blocks) + gemm1 (782 blocks)
__global__ __launch_bounds__(256) void bin_g1_kernel(const int* __restrict__ src,
                                                     const int* __restrict__ dst,
                                                     int* __restrict__ gcursor,
                                                     unsigned int* __restrict__ bst,
                                                     const float* __restrict__ x,
                                                     const unsigned short* __restrict__ w1bf,
                                                     unsigned short* __restrict__ hb) {
    __shared__ __align__(16) char sh[19472];   // max(bin 19460, Dt 17408)
    if (blockIdx.x < NBBIN) {
        bin_body(src, dst, gcursor, bst, blockIdx.x, sh);
    } else {
        gemm128_body_f32(x, w1bf, hb, blockIdx.x - NBBIN, sh);
    }
}

// ---------------- agg loop macro (128-feat bf16 rows, 16 lanes/group) ----------------

#define ACC8(G, W_) \
    acc[0] += W_ * bflo(G.x); acc[1] += W_ * bfhi(G.x); \
    acc[2] += W_ * bflo(G.y); acc[3] += W_ * bfhi(G.y); \
    acc[4] += W_ * bflo(G.z); acc[5] += W_ * bfhi(G.z); \
    acc[6] += W_ * bflo(G.w); acc[7] += W_ * bfhi(G.w);

#define AGG128_BODY(HV, RROW, C, DIW, LANE)                                         \
    {                                                                               \
        uint4 g = HV[(size_t)wid * 16 + (LANE)];                                    \
        float ws = (DIW) * (DIW);                                                   \
        acc[0] = ws * bflo(g.x); acc[1] = ws * bfhi(g.x);                           \
        acc[2] = ws * bflo(g.y); acc[3] = ws * bfhi(g.y);                           \
        acc[4] = ws * bflo(g.z); acc[5] = ws * bfhi(g.z);                           \
        acc[6] = ws * bflo(g.w); acc[7] = ws * bfhi(g.w);                           \
    }                                                                               \
    const int cfull = (C) & ~7;                                                     \
    uint4 q;                                                                        \
    if (cfull > 0) q = *(const uint4*)(RROW);                                       \
    for (int e = 0; e < cfull; e += 8) {                                            \
        uint4 qc = q;                                                               \
        if (e + 8 < cfull) q = *(const uint4*)((RROW) + e + 8);                     \
        int c0 = qc.x & 0xFFFFu, c1 = qc.x >> 16;                                   \
        int c2 = qc.y & 0xFFFFu, c3 = qc.y >> 16;                                   \
        int c4 = qc.z & 0xFFFFu, c5 = qc.z >> 16;                                   \
        int c6 = qc.w & 0xFFFFu, c7 = qc.w >> 16;                                   \
        uint4 g0 = HV[(size_t)c0 * 16 + (LANE)];                                    \
        uint4 g1 = HV[(size_t)c1 * 16 + (LANE)];                                    \
        uint4 g2 = HV[(size_t)c2 * 16 + (LANE)];                                    \
        uint4 g3 = HV[(size_t)c3 * 16 + (LANE)];                                    \
        uint4 g4 = HV[(size_t)c4 * 16 + (LANE)];                                    \
        uint4 g5 = HV[(size_t)c5 * 16 + (LANE)];                                    \
        uint4 g6 = HV[(size_t)c6 * 16 + (LANE)];                                    \
        uint4 g7 = HV[(size_t)c7 * 16 + (LANE)];                                    \
        float w0 = (DIW) * dinv[c0], w1 = (DIW) * dinv[c1];                         \
        float w2 = (DIW) * dinv[c2], w3 = (DIW) * dinv[c3];                         \
        float w4 = (DIW) * dinv[c4], w5 = (DIW) * dinv[c5];                         \
        float w6 = (DIW) * dinv[c6], w7 = (DIW) * dinv[c7];                         \
        ACC8(g0, w0) ACC8(g1, w1) ACC8(g2, w2) ACC8(g3, w3)                         \
        ACC8(g4, w4) ACC8(g5, w5) ACC8(g6, w6) ACC8(g7, w7)                         \
    }                                                                               \
    if ((C) & 7) {                                                                  \
        int e = cfull, rem = (C) - e;                                               \
        uint4 qc = *(const uint4*)((RROW) + e);                                     \
        int c0 = qc.x & 0xFFFFu, c1 = qc.x >> 16;                                   \
        int c2 = qc.y & 0xFFFFu, c3 = qc.y >> 16;                                   \
        int c4 = qc.z & 0xFFFFu, c5 = qc.z >> 16;                                   \
        int c6 = qc.w & 0xFFFFu, c7 = qc.w >> 16;                                   \
        if (rem <= 1) c1 = 0; if (rem <= 2) c2 = 0; if (rem <= 3) c3 = 0;           \
        if (rem <= 4) c4 = 0; if (rem <= 5) c5 = 0; if (rem <= 6) c6 = 0;           \
        c7 = 0;                                                                     \
        float w0 = (DIW) * dinv[c0];                                                \
        float w1 = (rem > 1) ? (DIW) * dinv[c1] : 0.f;                              \
        float w2 = (rem > 2) ? (DIW) * dinv[c2] : 0.f;                              \
        float w3 = (rem > 3) ? (DIW) * dinv[c3] : 0.f;                              \
        float w4 = (rem > 4) ? (DIW) * dinv[c4] : 0.f;                              \
        float w5 = (rem > 5) ? (DIW) * dinv[c5] : 0.f;                              \
        float w6 = (rem > 6) ? (DIW) * dinv[c6] : 0.f;                              \
        float w7 = 0.f;                                                             \
        uint4 g0 = HV[(size_t)c0 * 16 + (LANE)];                                    \
        uint4 g1 = HV[(size_t)c1 * 16 + (LANE)];                                    \
        uint4 g2 = HV[(size_t)c2 * 16 + (LANE)];                                    \
        uint4 g3 = HV[(size_t)c3 * 16 + (LANE)];                                    \
        uint4 g4 = HV[(size_t)c4 * 16 + (LANE)];                                    \
        uint4 g5 = HV[(size_t)c5 * 16 + (LANE)];                                    \
        uint4 g6 = HV[(size_t)c6 * 16 + (LANE)];                                    \
        uint4 g7 = HV[(size_t)c7 * 16 + (LANE)];                                    \
        ACC8(g0, w0) ACC8(g1, w1) ACC8(g2, w2) ACC8(g3, w3)                         \
        ACC8(g4, w4) ACC8(g5, w5) ACC8(g6, w6) ACC8(g7, w7)                         \
    }

// ---------------- fused layer-1 agg + layer-2 GEMM (32-node blocks, 8.7KB LDS) --------------

__global__ __launch_bounds__(256) void aggW2_kernel(const unsigned short* __restrict__ hin,
                                                    const unsigned short* __restrict__ raw,
                                                    const int* __restrict__ cnt_g,
                                                    const float* __restrict__ dinv,
                                                    const float* __restrict__ bias,
                                                    const unsigned short* __restrict__ Wbf,
                                                    unsigned short* __restrict__ out) {
    __shared__ unsigned short Zt[32 * 136];    // z1 tile bf16, later reused for D staging
    const int t = threadIdx.x;
    const int row0 = blockIdx.x * 32;
    const int group = t >> 4;
    const int lane  = t & 15;
    const uint4* hv = (const uint4*)hin;
    const float4* bp = (const float4*)bias;
    float4 bv0 = bp[lane * 2], bv1 = bp[lane * 2 + 1];

    for (int r = 0; r < 2; ++r) {
        const int wid = row0 + r * 16 + group;
        uint4 o = make_uint4(0u, 0u, 0u, 0u);
        if (wid < NN) {
            int c = cnt_g[wid];
            if (c > RAWSTRIDE) c = RAWSTRIDE;
            const float diw = dinv[wid];
            const unsigned short* rrow = raw + (size_t)wid * RAWSTRIDE;
            float acc[8];
            AGG128_BODY(hv, rrow, c, diw, lane)
            acc[0] += bv0.x; acc[1] += bv0.y; acc[2] += bv0.z; acc[3] += bv0.w;
            acc[4] += bv1.x; acc[5] += bv1.y; acc[6] += bv1.z; acc[7] += bv1.w;
            #pragma unroll
            for (int j = 0; j < 8; ++j) acc[j] = fmaxf(acc[j], 0.f);
            o.x = (unsigned int)f2bf(acc[0]) | ((unsigned int)f2bf(acc[1]) << 16);
            o.y = (unsigned int)f2bf(acc[2]) | ((unsigned int)f2bf(acc[3]) << 16);
            o.z = (unsigned int)f2bf(acc[4]) | ((unsigned int)f2bf(acc[5]) << 16);
            o.w = (unsigned int)f2bf(acc[6]) | ((unsigned int)f2bf(acc[7]) << 16);
        }
        *(uint4*)&Zt[(r * 16 + group) * 136 + lane * 8] = o;
    }
    __syncthreads();

    // MFMA: 4 waves split (row-half rh, nt-half nh); B-frags from global packed W2
    const int wave = t >> 6;
    const int l64  = t & 63;
    const int m16  = l64 & 15;
    const int quad = l64 >> 4;
    const int rh = wave & 1;
    const int nh = wave >> 1;

    f4v acc[4];
    #pragma unroll
    for (int i = 0; i < 4; ++i) acc[i] = (f4v)(0.0f);

    #pragma unroll
    for (int k0 = 0; k0 < 128; k0 += 32) {
        bf8v afrag = *(const bf8v*)&Zt[(rh * 16 + m16) * 136 + k0 + quad * 8];
        #pragma unroll
        for (int j = 0; j < 4; ++j) {
            int nt = nh * 4 + j;
            bf8v bfrag = *(const bf8v*)(Wbf + (nt * 16 + m16) * 128 + k0 + quad * 8);
            acc[j] = __builtin_amdgcn_mfma_f32_16x16x32_bf16(afrag, bfrag, acc[j], 0, 0, 0);
        }
    }
    __syncthreads();   // all Zt reads done before D staging overwrites it

    #pragma unroll
    for (int j = 0; j < 4; ++j) {
        #pragma unroll
        for (int rr = 0; rr < 4; ++rr) {
            Zt[(rh * 16 + quad * 4 + rr) * 136 + (nh * 4 + j) * 16 + m16] = f2bf(acc[j][rr]);
        }
    }
    __syncthreads();

    #pragma unroll
    for (int jj = 0; jj < 2; ++jj) {
        int idx = jj * 256 + t;
        int r = idx >> 4, c4 = idx & 15;
        int gr = row0 + r;
        if (gr < NN)
            ((uint4*)(out + (size_t)gr * 128))[c4] = ((const uint4*)&Zt[r * 136])[c4];
    }
}

// ---------------- fused layer-2 agg + layer-3 GEMM (32-node blocks, fp32 compute) -----------

__global__ __launch_bounds__(256) void aggG3_kernel(const unsigned short* __restrict__ hin,
                                                    const unsigned short* __restrict__ raw,
                                                    const int* __restrict__ cnt_g,
                                                    const float* __restrict__ dinv,
                                                    const float* __restrict__ bias,
                                                    const float* __restrict__ W,
                                                    unsigned short* __restrict__ outh) {
    __shared__ unsigned short Zt[32 * 136];    // z2 tile bf16
    const int t = threadIdx.x;
    const int row0 = blockIdx.x * 32;
    const int group = t >> 4;
    const int lane  = t & 15;
    const uint4* hv = (const uint4*)hin;
    const float4* bp = (const float4*)bias;
    float4 bv0 = bp[lane * 2], bv1 = bp[lane * 2 + 1];

    for (int r = 0; r < 2; ++r) {
        const int wid = row0 + r * 16 + group;
        uint4 o = make_uint4(0u, 0u, 0u, 0u);
        if (wid < NN) {
            int c = cnt_g[wid];
            if (c > RAWSTRIDE) c = RAWSTRIDE;
            const float diw = dinv[wid];
            const unsigned short* rrow = raw + (size_t)wid * RAWSTRIDE;
            float acc[8];
            AGG128_BODY(hv, rrow, c, diw, lane)
            acc[0] += bv0.x; acc[1] += bv0.y; acc[2] += bv0.z; acc[3] += bv0.w;
            acc[4] += bv1.x; acc[5] += bv1.y; acc[6] += bv1.z; acc[7] += bv1.w;
            #pragma unroll
            for (int j = 0; j < 8; ++j) acc[j] = fmaxf(acc[j], 0.f);
            o.x = (unsigned int)f2bf(acc[0]) | ((unsigned int)f2bf(acc[1]) << 16);
            o.y = (unsigned int)f2bf(acc[2]) | ((unsigned int)f2bf(acc[3]) << 16);
            o.z = (unsigned int)f2bf(acc[4]) | ((unsigned int)f2bf(acc[5]) << 16);
            o.w = (unsigned int)f2bf(acc[6]) | ((unsigned int)f2bf(acc[7]) << 16);
        }
        *(uint4*)&Zt[(r * 16 + group) * 136 + lane * 8] = o;
    }
    __syncthreads();

    // fp32 GEMM: h3 = z2 @ W3, W3 [128][64]; 16 col-groups x 16 row-threads x 2 rows
    const int cg = t & 15;
    const int rt = t >> 4;
    const float4* Wv = (const float4*)W;
    float4 acc[2];
    acc[0] = make_float4(0.f, 0.f, 0.f, 0.f);
    acc[1] = make_float4(0.f, 0.f, 0.f, 0.f);

    for (int k0 = 0; k0 < 128; k0 += 4) {
        float4 w0 = Wv[(k0 + 0) * 16 + cg];
        float4 w1 = Wv[(k0 + 1) * 16 + cg];
        float4 w2 = Wv[(k0 + 2) * 16 + cg];
        float4 w3 = Wv[(k0 + 3) * 16 + cg];
        #pragma unroll
        for (int i = 0; i < 2; ++i) {
            uint2 u = *(const uint2*)&Zt[(rt * 2 + i) * 136 + k0];
            float ax = bflo(u.x), ay = bfhi(u.x), az = bflo(u.y), aw = bfhi(u.y);
            acc[i].x += ax * w0.x + ay * w1.x + az * w2.x + aw * w3.x;
            acc[i].y += ax * w0.y + ay * w1.y + az * w2.y + aw * w3.y;
            acc[i].z += ax * w0.z + ay * w1.z + az * w2.z + aw * w3.z;
            acc[i].w += ax * w0.w + ay * w1.w + az * w2.w + aw * w3.w;
        }
    }

    #pragma unroll
    for (int i = 0; i < 2; ++i) {
        int gr = row0 + rt * 2 + i;
        if (gr < NN) {
            uint2 o;
            o.x = (unsigned int)f2bf(acc[i].x) | ((unsigned int)f2bf(acc[i].y) << 16);
            o.y = (unsigned int)f2bf(acc[i].z) | ((unsigned int)f2bf(acc[i].w) << 16);
            ((uint2*)(outh + (size_t)gr * 64))[cg] = o;
        }
    }
}

// ---------------- layer-3 aggregation: bf16 gather (128B rows) -> fp32 out ----------------

__global__ __launch_bounds__(256) void agg3_kernel(const unsigned short* __restrict__ hin,
                                                   const unsigned short* __restrict__ raw,
                                                   const int* __restrict__ cnt_g,
                                                   const float* __restrict__ dinv,
                                                   const float* __restrict__ bias,
                                                   float* __restrict__ out) {
    const int t = threadIdx.x;
    const int group = t >> 3;
    const int lane  = t & 7;
    const int wid = blockIdx.x * 32 + group;
    if (wid >= NN) return;

    int c = cnt_g[wid];
    if (c > RAWSTRIDE) c = RAWSTRIDE;
    const float diw = dinv[wid];
    const unsigned short* rrow = raw + (size_t)wid * RAWSTRIDE;
    const uint4* hv = (const uint4*)hin;      // 8 uint4 per 64-feat bf16 row

    float acc[8];
    {   // self loop
        uint4 g = hv[(size_t)wid * 8 + lane];
        float ws = diw * diw;
        acc[0] = ws * bflo(g.x); acc[1] = ws * bfhi(g.x);
        acc[2] = ws * bflo(g.y); acc[3] = ws * bfhi(g.y);
        acc[4] = ws * bflo(g.z); acc[5] = ws * bfhi(g.z);
        acc[6] = ws * bflo(g.w); acc[7] = ws * bfhi(g.w);
    }

    const int cfull = c & ~7;
    uint4 q;
    if (cfull > 0) q = *(const uint4*)(rrow);
    for (int e = 0; e < cfull; e += 8) {
        uint4 qc = q;
        if (e + 8 < cfull) q = *(const uint4*)(rrow + e + 8);
        int c0 = qc.x & 0xFFFFu, c1 = qc.x >> 16;
        int c2 = qc.y & 0xFFFFu, c3 = qc.y >> 16;
        int c4 = qc.z & 0xFFFFu, c5 = qc.z >> 16;
        int c6 = qc.w & 0xFFFFu, c7 = qc.w >> 16;
        uint4 g0 = hv[(size_t)c0 * 8 + lane];
        uint4 g1 = hv[(size_t)c1 * 8 + lane];
        uint4 g2 = hv[(size_t)c2 * 8 + lane];
        uint4 g3 = hv[(size_t)c3 * 8 + lane];
        uint4 g4 = hv[(size_t)c4 * 8 + lane];
        uint4 g5 = hv[(size_t)c5 * 8 + lane];
        uint4 g6 = hv[(size_t)c6 * 8 + lane];
        uint4 g7 = hv[(size_t)c7 * 8 + lane];
        float w0 = diw * dinv[c0], w1 = diw * dinv[c1];
        float w2 = diw * dinv[c2], w3 = diw * dinv[c3];
        float w4 = diw * dinv[c4], w5 = diw * dinv[c5];
        float w6 = diw * dinv[c6], w7 = diw * dinv[c7];
        ACC8(g0, w0) ACC8(g1, w1) ACC8(g2, w2) ACC8(g3, w3)
        ACC8(g4, w4) ACC8(g5, w5) ACC8(g6, w6) ACC8(g7, w7)
    }
    if (c & 7) {
        int e = cfull, rem = c - e;
        uint4 qc = *(const uint4*)(rrow + e);
        int c0 = qc.x & 0xFFFFu, c1 = qc.x >> 16;
        int c2 = qc.y & 0xFFFFu, c3 = qc.y >> 16;
        int c4 = qc.z & 0xFFFFu, c5 = qc.z >> 16;
        int c6 = qc.w & 0xFFFFu, c7 = qc.w >> 16;
        if (rem <= 1) c1 = 0; if (rem <= 2) c2 = 0; if (rem <= 3) c3 = 0;
        if (rem <= 4) c4 = 0; if (rem <= 5) c5 = 0; if (rem <= 6) c6 = 0;
        c7 = 0;
        float w0 = diw * dinv[c0];
        float w1 = (rem > 1) ? diw * dinv[c1] : 0.f;
        float w2 = (rem > 2) ? diw * dinv[c2] : 0.f;
        float w3 = (rem > 3) ? diw * dinv[c3] : 0.f;
        float w4 = (rem > 4) ? diw * dinv[c4] : 0.f;
        float w5 = (rem > 5) ? diw * dinv[c5] : 0.f;
        float w6 = (rem > 6) ? diw * dinv[c6] : 0.f;
        float w7 = 0.f;
        uint4 g0 = hv[(size_t)c0 * 8 + lane];
        uint4 g1 = hv[(size_t)c1 * 8 + lane];
        uint4 g2 = hv[(size_t)c2 * 8 + lane];
        uint4 g3 = hv[(size_t)c3 * 8 + lane];
        uint4 g4 = hv[(size_t)c4 * 8 + lane];
        uint4 g5 = hv[(size_t)c5 * 8 + lane];
        uint4 g6 = hv[(size_t)c6 * 8 + lane];
        uint4 g7 = hv[(size_t)c7 * 8 + lane];
        ACC8(g0, w0) ACC8(g1, w1) ACC8(g2, w2) ACC8(g3, w3)
        ACC8(g4, w4) ACC8(g5, w5) ACC8(g6, w6) ACC8(g7, w7)
    }

    const float4* bp = (const float4*)bias;
    float4 b0 = bp[lane * 2], b1 = bp[lane * 2 + 1];
    acc[0] += b0.x; acc[1] += b0.y; acc[2] += b0.z; acc[3] += b0.w;
    acc[4] += b1.x; acc[5] += b1.y; acc[6] += b1.z; acc[7] += b1.w;

    float4 o0 = make_float4(acc[0], acc[1], acc[2], acc[3]);
    float4 o1 = make_float4(acc[4], acc[5], acc[6], acc[7]);
    ((float4*)(out + (size_t)wid * 64))[lane * 2]     = o0;
    ((float4*)(out + (size_t)wid * 64))[lane * 2 + 1] = o1;
}

// ---------------- launch ----------------

extern "C" void kernel_launch(void* const* d_in, const int* in_sizes, int n_in,
                              void* d_out, int out_size, void* d_ws, size_t ws_size,
                              hipStream_t stream) {
    const float* x  = (const float*)d_in[0];
    const int*   ei = (const int*)d_in[1];     // [2, NE], row0=src, row1=dst
    const float* W1 = (const float*)d_in[2];
    const float* b1 = (const float*)d_in[3];
    const float* W2 = (const float*)d_in[4];
    const float* b2 = (const float*)d_in[5];
    const float* W3 = (const float*)d_in[6];
    const float* b3 = (const float*)d_in[7];
    float* out = (float*)d_out;

    // Workspace map:
    //   cnt_g   @ 0x0000000  200,000 B
    //   gcursor @ 0x0040000  784 B        (zeroed by prep_kernel)
    //   dinv    @ 0x0048000  200,000 B
    //   w1bf    @ 0x0080000  32,768 B     (bf16 [n][k] packed W1)
    //   w2bf    @ 0x0088000  32,768 B
    //   bst     @ 0x0090000  3,612,672 B
    //   raw     @ 0x0480000  9,600,000 B
    //   hb      @ 0x0E00000  12,800,000 B   (gemm1 out)
    //   h2b     @ 0x1B00000  12,800,000 B   (aggW2 out)
    //   h3b     @ 0x2800000   6,400,000 B   (aggG3 out)   (~48 MB total)
    char* w = (char*)d_ws;
    int*   cnt_g   = (int*)  (w + 0x0000000);
    int*   gcursor = (int*)  (w + 0x0040000);
    float* dinv    = (float*)(w + 0x0048000);
    unsigned int*   w1p = (unsigned int*)  (w + 0x0080000);
    unsigned int*   w2p = (unsigned int*)  (w + 0x0088000);
    unsigned int*   bst = (unsigned int*)  (w + 0x0090000);
    unsigned short* raw = (unsigned short*)(w + 0x0480000);
    unsigned short* hb  = (unsigned short*)(w + 0x0E00000);
    unsigned short* h2b = (unsigned short*)(w + 0x1B00000);
    unsigned short* h3b = (unsigned short*)(w + 0x2800000);

    const int* src = ei;
    const int* dst = ei + NE;

    // pack W1,W2 to bf16 + zero gcursor (replaces memset)
    prep_kernel<<<64, 256, 0, stream>>>(W1, W2, w1p, w2p, gcursor);
    // fused: CSR binning + layer-1 GEMM (independent)
    bin_g1_kernel<<<NBBIN + G1B, 256, 0, stream>>>(src, dst, gcursor, bst, x,
                                                   (const unsigned short*)w1p, hb);
    sortb_kernel<<<NBUCK, 512, 0, stream>>>(gcursor, bst, cnt_g, dinv, raw);
    // fused layer-1 agg + layer-2 GEMM (32-node blocks)
    aggW2_kernel<<<G2B, 256, 0, stream>>>(hb, raw, cnt_g, dinv, b1,
                                          (const unsigned short*)w2p, h2b);
    // fused layer-2 agg + layer-3 GEMM (32-node blocks)
    aggG3_kernel<<<G2B, 256, 0, stream>>>(h2b, raw, cnt_g, dinv, b2, W3, h3b);
    // final aggregation straight to output
    agg3_kernel<<<(NN + 31) / 32, 256, 0, stream>>>(h3b, raw, cnt_g, dinv, b3, out);
}